// Round 13
// baseline (899.370 us; speedup 1.0000x reference)
//
#include <hip/hip_runtime.h>
#include <hip/hip_bf16.h>
#include <math.h>

// Problem dims (fixed by reference)
#define NTOK 98304      // 32768 * 3
#define DIN  256
#define DE   512
#define DH   512
#define DC   64
#define NCODE 1024
#define CHUNK 49152     // tokens per pipeline chunk (2 chunks)
#define DWCHUNK 1024    // tokens per dw block (skew-proof: hot code gets 96 blocks)
#define HBLK 96         // histogram blocks (1024 tokens each)

typedef _Float16 half8 __attribute__((ext_vector_type(8)));
typedef float f32x4 __attribute__((ext_vector_type(4)));

// fast gelu (tanh approximation): gelu(x) = x * sigmoid(2*k0*(x + k1 x^3)).
// HW exp2 + rcp, ~8 VALU instrs vs ~30 libm tanhf (round 12: −9 µs/dispatch,
// VALUBusy 49->31, absmax unchanged).
__device__ __forceinline__ float gelu_f(float x) {
    const float k1 = 0.044715f;
    // C = -2*log2(e)*sqrt(2/pi)
    const float C = -(2.0f * 1.4426950408889634f * 0.7978845608028654f);
    float q = x * x;
    float r = fmaf(k1, q, 1.0f);          // 1 + k1 x^2
    float t = x * r * C;                  // -2*log2e*u
    float e = __builtin_amdgcn_exp2f(t);  // exp(-2u)
    float s = __builtin_amdgcn_rcpf(e + 1.0f);   // sigmoid(2u)
    return x * s;
}

// async global->LDS, 16B per lane (LDS dest = wave-uniform base + lane*16)
__device__ __forceinline__ void gload_lds16(const _Float16* g, _Float16* l) {
    __builtin_amdgcn_global_load_lds(
        (const __attribute__((address_space(1))) void*)g,
        (__attribute__((address_space(3))) void*)l, 16, 0, 0);
}

__device__ __forceinline__ void raw_barrier() {
    asm volatile("s_barrier" ::: "memory");
}
__device__ __forceinline__ void lgkm0_barrier() {
    asm volatile("s_waitcnt lgkmcnt(0)" ::: "memory");
    asm volatile("s_barrier" ::: "memory");
}

// W[K][N] fp32 -> fragment-major hi/lo fp16 planes: P[(k>>3)*N*8 + n*8 + (k&7)]
__global__ __launch_bounds__(256)
void transpose_split_fm(const float* __restrict__ W, _Float16* __restrict__ Bh,
                        _Float16* __restrict__ Bl, int K, int N)
{
    int e = blockIdx.x * 256 + threadIdx.x;
    if (e >= K * N) return;
    int k = e / N, n = e % N;
    float v = W[e];
    _Float16 h = (_Float16)v;
    _Float16 l = (_Float16)(v - (float)h);
    size_t o = ((size_t)(k >> 3) * N + n) * 8 + (k & 7);
    Bh[o] = h; Bl[o] = l;
}

// ======================= MLP GEMM (fp16x3 MFMA, global_load_lds staging) =====
// Round-7 proven 2-barriers-per-K-step structure. Round 13: BK templated.
// L1/L2 use BN=64/BK=64 (48KB LDS, still 3 blocks/CU): HALF the barrier
// drains over K=512 (8 pairs instead of 16), 3072-block grid for TLP.
// Accumulation order per output element is identical (two 32-K sub-steps in
// sequence) -> bit-identical results. XCD swizzle: all N-blocks sharing an
// A-panel -> same XCD L2, temporally adjacent (round 11: FETCH 199->62 MB).
template<int BN, int BK, bool A_FM, bool EMIT_FM>
__global__ __launch_bounds__(256, 2)
void gemm_fm(const void* __restrict__ A0, const void* __restrict__ A1,
             const _Float16* __restrict__ Bhp, const _Float16* __restrict__ Blp,
             const float* __restrict__ bias,
             void* __restrict__ C0, void* __restrict__ C1,
             int M, int N, int K)
{
    constexpr int BM = 128;
    constexpr int WGM = (BN == 128) ? 2 : 4;
    constexpr int WAVE_M = BM / WGM;
    constexpr int MT = WAVE_M / 16;
    constexpr int NT = 4;
    constexpr int NSHIFT = (BN == 128) ? 7 : 6;
    constexpr int KB = BK / 8;                 // fragment-groups per K-step
    constexpr int AJ = (BM * BK) / 2048;       // A 16B-chunks per plane / 256thr
    constexpr int BJ = (BN * BK) / 2048;       // B 16B-chunks per plane / 256thr

    __shared__ __align__(16) _Float16 As[2][KB][BM][8];
    __shared__ __align__(16) _Float16 Bs[2][KB][BN][8];

    const int tid  = threadIdx.x;
    const int lane = tid & 63, wid = tid >> 6;
    const int lm   = lane & 15, quad = lane >> 4;
    const int wave_m = (BN == 128) ? (wid & 1) * 64 : wid * 32;
    const int wave_n = (BN == 128) ? (wid >> 1) * 64 : 0;

    // ---- XCD-aware swizzle (bijective; requires gridDim.y % 8 == 0) ----
    int bx = blockIdx.x, by = blockIdx.y;
    if (gridDim.x == 4 && (gridDim.y & 7) == 0) {
        int L = by * 4 + bx;          // linear dispatch id (x-fastest)
        int c = L & 7, w = L >> 3;
        bx = w & 3;                   // member (N-block) 0..3
        by = (w >> 2) * 8 + c;        // A-panel
    } else if (gridDim.x == 8 && (gridDim.y & 7) == 0) {
        int L = by * 8 + bx;
        int c = L & 7, k = L >> 3;
        bx = k & 7;                   // member (N-block) 0..7
        by = (k >> 3) * 8 + c;        // A-panel: ids == c (mod 8), 64-id window
    }
    const int m0 = by * BM, n0 = bx * BN;

    f32x4 acc[MT][NT];
#pragma unroll
    for (int mi = 0; mi < MT; ++mi)
#pragma unroll
        for (int ni = 0; ni < NT; ++ni) acc[mi][ni] = (f32x4)(0.f);

    for (int k0 = 0; k0 < K; k0 += BK) {
        const int kb0 = k0 >> 3;

        // ---- stage A ----
        if (A_FM) {
            const _Float16* ap[2] = {(const _Float16*)A0, (const _Float16*)A1};
#pragma unroll
            for (int p = 0; p < 2; ++p)
#pragma unroll
                for (int j = 0; j < AJ; ++j) {
                    int e  = j * 256 + tid;
                    int kb = e >> 7, tk = e & 127;
                    const _Float16* src = ap[p] + ((size_t)(kb0 + kb) * M + m0 + tk) * 8;
                    int eb = j * 256 + (tid & ~63);
                    gload_lds16(src, &As[p][eb >> 7][eb & 127][0]);
                }
        } else {
            // fp32 A (states): reg-stage + hi/lo split (BK=32 path)
            const float* A = (const float*)A0;
#pragma unroll
            for (int i = 0; i < 4; ++i) {
                int s = tid + i * 256;
                int row = s >> 3, kc = (s & 7) * 4;
                int kb = kc >> 3, off = kc & 7;
                float4 v = *(const float4*)(A + (size_t)(m0 + row) * K + k0 + kc);
                float vv[4] = {v.x, v.y, v.z, v.w};
                unsigned short h[4], l[4];
#pragma unroll
                for (int j = 0; j < 4; ++j) {
                    _Float16 hh = (_Float16)vv[j];
                    _Float16 ll = (_Float16)(vv[j] - (float)hh);
                    h[j] = __builtin_bit_cast(unsigned short, hh);
                    l[j] = __builtin_bit_cast(unsigned short, ll);
                }
                uint2 ph, pl;
                ph.x = (unsigned int)h[0] | ((unsigned int)h[1] << 16);
                ph.y = (unsigned int)h[2] | ((unsigned int)h[3] << 16);
                pl.x = (unsigned int)l[0] | ((unsigned int)l[1] << 16);
                pl.y = (unsigned int)l[2] | ((unsigned int)l[3] << 16);
                *(uint2*)&As[0][kb][row][off] = ph;
                *(uint2*)&As[1][kb][row][off] = pl;
            }
        }

        // ---- stage B (always fragment-major planes) ----
        {
            const _Float16* bp[2] = {Bhp, Blp};
#pragma unroll
            for (int p = 0; p < 2; ++p)
#pragma unroll
                for (int j = 0; j < BJ; ++j) {
                    int e  = j * 256 + tid;
                    int kb = e >> NSHIFT, n = e & (BN - 1);
                    const _Float16* src = bp[p] + ((size_t)(kb0 + kb) * N + n0 + n) * 8;
                    int eb = j * 256 + (tid & ~63);
                    gload_lds16(src, &Bs[p][eb >> NSHIFT][eb & (BN - 1)][0]);
                }
        }
        __syncthreads();

#pragma unroll
        for (int ks = 0; ks < BK / 32; ++ks) {
            half8 ahf[MT], alf[MT], bhf[NT], blf[NT];
#pragma unroll
            for (int mi = 0; mi < MT; ++mi) {
                int r = wave_m + mi * 16 + lm;
                ahf[mi] = *(const half8*)&As[0][ks * 4 + quad][r][0];
                alf[mi] = *(const half8*)&As[1][ks * 4 + quad][r][0];
            }
#pragma unroll
            for (int ni = 0; ni < NT; ++ni) {
                int c = wave_n + ni * 16 + lm;
                bhf[ni] = *(const half8*)&Bs[0][ks * 4 + quad][c][0];
                blf[ni] = *(const half8*)&Bs[1][ks * 4 + quad][c][0];
            }
#pragma unroll
            for (int mi = 0; mi < MT; ++mi)
#pragma unroll
                for (int ni = 0; ni < NT; ++ni) {
                    acc[mi][ni] = __builtin_amdgcn_mfma_f32_16x16x32_f16(ahf[mi], bhf[ni], acc[mi][ni], 0, 0, 0);
                    acc[mi][ni] = __builtin_amdgcn_mfma_f32_16x16x32_f16(ahf[mi], blf[ni], acc[mi][ni], 0, 0, 0);
                    acc[mi][ni] = __builtin_amdgcn_mfma_f32_16x16x32_f16(alf[mi], bhf[ni], acc[mi][ni], 0, 0, 0);
                }
        }
        __syncthreads();
    }

#pragma unroll
    for (int ni = 0; ni < NT; ++ni) {
        int col = n0 + wave_n + ni * 16 + lm;
        float bv = bias[col];
        size_t slab = EMIT_FM ? ((size_t)(col >> 3) * M * 8 + (col & 7)) : 0;
#pragma unroll
        for (int mi = 0; mi < MT; ++mi) {
            int rowbase = m0 + wave_m + mi * 16 + quad * 4;
#pragma unroll
            for (int r = 0; r < 4; ++r) {
                float g = gelu_f(acc[mi][ni][r] + bv);
                if (EMIT_FM) {
                    _Float16 hh = (_Float16)g;
                    _Float16 ll = (_Float16)(g - (float)hh);
                    size_t oo = slab + (size_t)(rowbase + r) * 8;
                    ((_Float16*)C0)[oo] = hh;
                    ((_Float16*)C1)[oo] = ll;
                } else {
                    ((float*)C0)[(size_t)(rowbase + r) * N + col] = g;
                }
            }
        }
    }
}

// ======================= VQ prep =======================
__global__ __launch_bounds__(256)
void prep_emb(const float* __restrict__ emb, _Float16* __restrict__ ebh,
              _Float16* __restrict__ ebl, float* __restrict__ embT)
{
    int e = blockIdx.x * 256 + threadIdx.x;   // 65536
    int c = e >> 10, n = e & 1023;
    float v = emb[e];
    _Float16 h = (_Float16)v;
    _Float16 l = (_Float16)(v - (float)h);
    ebh[(size_t)n * DC + c] = h;
    ebl[(size_t)n * DC + c] = l;
    embT[(size_t)n * DC + c] = v;
}

__global__ __launch_bounds__(256)
void e2_kernel(const float* __restrict__ emb, float* __restrict__ e2)
{
    int n = blockIdx.x * 256 + threadIdx.x;   // 1024
    float s = 0.f;
#pragma unroll
    for (int c = 0; c < DC; ++c) { float e = emb[(size_t)c * NCODE + n]; s = fmaf(e, e, s); }
    e2[n] = s;
}

// ======================= VQ distance+argmin (MFMA fp16x4, NO atomics) =========
__global__ __launch_bounds__(256, 2)
void vq_dist_kernel(const float* __restrict__ lat,
                    const _Float16* __restrict__ ebh, const _Float16* __restrict__ ebl,
                    const float* __restrict__ e2,
                    float* __restrict__ encidx_out, int* __restrict__ codes_out)
{
    __shared__ __align__(16) char Bt[16384];   // staged tile: hi 8KB + lo 8KB (swizzled)
    __shared__ float e2s[NCODE];               // 4096 B

    const int tid = threadIdx.x, lane = tid & 63, wave = tid >> 6;
    const int lm = lane & 15, quad = lane >> 4;
    const int tok0 = blockIdx.x * 128;

    // ---- A fragments: load directly from lat (fp32), split to hi/lo fp16 ----
    half8 ah[2][2], al[2][2];   // [mt][ks]
#pragma unroll
    for (int mt = 0; mt < 2; ++mt)
#pragma unroll
        for (int ks = 0; ks < 2; ++ks) {
            const float* ap = lat + (size_t)(tok0 + wave * 32 + mt * 16 + lm) * DC + ks * 32 + quad * 8;
            float4 v0 = *(const float4*)ap;
            float4 v1 = *(const float4*)(ap + 4);
            float vv[8] = {v0.x, v0.y, v0.z, v0.w, v1.x, v1.y, v1.z, v1.w};
            half8 hh, ll;
#pragma unroll
            for (int j = 0; j < 8; ++j) {
                _Float16 h = (_Float16)vv[j];
                hh[j] = h;
                ll[j] = (_Float16)(vv[j] - (float)h);
            }
            ah[mt][ks] = hh;
            al[mt][ks] = ll;
        }

    // e2 table -> LDS
#pragma unroll
    for (int i = 0; i < 4; ++i) { int k = tid + i * 256; e2s[k] = e2[k]; }

    const _Float16* srcbase[4];
    int ldsoff[4];
#pragma unroll
    for (int k = 0; k < 4; ++k) {
        int S = tid + (k << 8);
        int r = (S & 511) >> 3, c16 = S & 7;
        srcbase[k] = ((S < 512) ? ebh : ebl) + (r << 6) + (c16 << 3);
        ldsoff[k] = ((S >> 9) << 13) + (r << 7) + ((c16 ^ (r & 7)) << 4);
    }

    uint4 stg[4];
#pragma unroll
    for (int k = 0; k < 4; ++k) stg[k] = *(const uint4*)(srcbase[k]);           // tile 0
#pragma unroll
    for (int k = 0; k < 4; ++k) *(uint4*)(Bt + ldsoff[k]) = stg[k];
#pragma unroll
    for (int k = 0; k < 4; ++k) stg[k] = *(const uint4*)(srcbase[k] + 4096);    // tile 1
    lgkm0_barrier();

    const char* Bhi = (const char*)Bt;
    const char* Blo = (const char*)Bt + 8192;

    f32x4 acc[2][4];
    float bd[2][4]; int bi[2][4];
#pragma unroll
    for (int mt = 0; mt < 2; ++mt)
#pragma unroll
        for (int r = 0; r < 4; ++r) { bd[mt][r] = INFINITY; bi[mt][r] = 0; }

    for (int t = 0; t < 16; ++t) {
        const int k0 = t * 64;
#pragma unroll
        for (int mt = 0; mt < 2; ++mt)
#pragma unroll
            for (int ni = 0; ni < 4; ++ni) acc[mt][ni] = (f32x4)(0.f);

#pragma unroll
        for (int ks = 0; ks < 2; ++ks) {
            half8 bh[4], bl[4];
#pragma unroll
            for (int ni = 0; ni < 4; ++ni) {
                int cl = ni * 16 + lm;
                int sw = ((ks * 4 + quad) ^ (cl & 7)) << 4;
                bh[ni] = *(const half8*)(Bhi + (cl << 7) + sw);
                bl[ni] = *(const half8*)(Blo + (cl << 7) + sw);
            }
#pragma unroll
            for (int ni = 0; ni < 4; ++ni)
#pragma unroll
                for (int mt = 0; mt < 2; ++mt) {
                    acc[mt][ni] = __builtin_amdgcn_mfma_f32_16x16x32_f16(ah[mt][ks], bh[ni], acc[mt][ni], 0, 0, 0);
                    acc[mt][ni] = __builtin_amdgcn_mfma_f32_16x16x32_f16(ah[mt][ks], bl[ni], acc[mt][ni], 0, 0, 0);
                    acc[mt][ni] = __builtin_amdgcn_mfma_f32_16x16x32_f16(al[mt][ks], bh[ni], acc[mt][ni], 0, 0, 0);
                    acc[mt][ni] = __builtin_amdgcn_mfma_f32_16x16x32_f16(al[mt][ks], bl[ni], acc[mt][ni], 0, 0, 0);
                }
        }

#pragma unroll
        for (int ni = 0; ni < 4; ++ni) {
            int code = k0 + ni * 16 + lm;
            float ee = e2s[code];
#pragma unroll
            for (int mt = 0; mt < 2; ++mt)
#pragma unroll
                for (int r = 0; r < 4; ++r) {
                    float d = ee - 2.f * acc[mt][ni][r];
                    if (d < bd[mt][r]) { bd[mt][r] = d; bi[mt][r] = code; }
                }
        }

        raw_barrier();
        if (t < 15) {
#pragma unroll
            for (int k = 0; k < 4; ++k) *(uint4*)(Bt + ldsoff[k]) = stg[k];    // tile t+1
            if (t < 14) {
#pragma unroll
                for (int k = 0; k < 4; ++k)
                    stg[k] = *(const uint4*)(srcbase[k] + (size_t)(t + 2) * 4096);
            }
            lgkm0_barrier();
        }
    }

    // argmin across the 16 lanes of each quad-group via shfl_xor
#pragma unroll
    for (int mt = 0; mt < 2; ++mt)
#pragma unroll
        for (int r = 0; r < 4; ++r) {
            float d = bd[mt][r]; int i0 = bi[mt][r];
#pragma unroll
            for (int off = 1; off < 16; off <<= 1) {
                float od = __shfl_xor(d, off, 64);
                int   oi = __shfl_xor(i0, off, 64);
                if (od < d || (od == d && oi < i0)) { d = od; i0 = oi; }
            }
            if (lm == 0) {
                int tok = tok0 + wave * 32 + mt * 16 + quad * 4 + r;
                encidx_out[tok] = (float)i0;
                codes_out[tok] = i0;
            }
        }
}

// ======================= histogram + rank (non-atomic counts) ================
__global__ __launch_bounds__(256)
void hist_rank_kernel(const int* __restrict__ codes, int* __restrict__ crank,
                      unsigned int* __restrict__ hist2d)
{
    __shared__ unsigned int hist[NCODE];
    const int tid = threadIdx.x, b = blockIdx.x;
#pragma unroll
    for (int j = 0; j < 4; ++j) hist[tid + j * 256] = 0;
    __syncthreads();
#pragma unroll
    for (int j = 0; j < 4; ++j) {
        int t = b * 1024 + j * 256 + tid;
        int c = codes[t];
        crank[t] = (int)atomicAdd(&hist[c], 1u);   // LDS atomic
    }
    __syncthreads();
#pragma unroll
    for (int j = 0; j < 4; ++j) {
        int k = tid + j * 256;
        hist2d[(size_t)b * NCODE + k] = hist[k];
    }
}

// ======================= scan: counts, offs, per-block bases =================
__global__ __launch_bounds__(1024)
void scan_kernel(const unsigned int* __restrict__ hist2d,
                 unsigned int* __restrict__ counts, int* __restrict__ offs,
                 int* __restrict__ base2d)
{
    __shared__ int s[1024];
    const int t = threadIdx.x;
    int v = 0;
    for (int b = 0; b < HBLK; ++b) v += (int)hist2d[(size_t)b * NCODE + t];
    counts[t] = (unsigned int)v;
    s[t] = v; __syncthreads();
    for (int d = 1; d < 1024; d <<= 1) {
        int x = (t >= d) ? s[t - d] : 0;
        __syncthreads();
        s[t] += x;
        __syncthreads();
    }
    int run = s[t] - v;          // exclusive prefix
    offs[t] = run;
    for (int b = 0; b < HBLK; ++b) {
        base2d[(size_t)b * NCODE + t] = run;
        run += (int)hist2d[(size_t)b * NCODE + t];
    }
}

// ======================= scatter (atomic-free) ===============================
__global__ __launch_bounds__(256)
void scatter_kernel(const int* __restrict__ codes, const int* __restrict__ crank,
                    const int* __restrict__ base2d, int* __restrict__ bucket)
{
    const int tid = threadIdx.x, b = blockIdx.x;
#pragma unroll
    for (int j = 0; j < 4; ++j) {
        int t = b * 1024 + j * 256 + tid;
        int c = codes[t];
        bucket[base2d[(size_t)b * NCODE + c] + crank[t]] = t;
    }
}

// ======================= VQ quantize + e_latent_loss (coalesced) =============
__global__ __launch_bounds__(256)
void vq_quant_kernel(const float* __restrict__ lat, const float* __restrict__ embT,
                     const int* __restrict__ codes,
                     float* __restrict__ quant_out, float* __restrict__ sum_sq)
{
    __shared__ int scod[256];
    __shared__ float wred[4];
    const int tid = threadIdx.x, lane = tid & 63, wv = tid >> 6;
    const int tokb = blockIdx.x * 256;

    scod[tid] = codes[tokb + tid];
    __syncthreads();

    const int t0 = wv * 64;            // this wave's 64 tokens (block-local)
    float lsum = 0.f;
#pragma unroll
    for (int i = 0; i < 64; i += 4) {
        float q[4], x[4];
#pragma unroll
        for (int j = 0; j < 4; ++j) {
            int c = scod[t0 + i + j];
            q[j] = embT[(size_t)c * DC + lane];
        }
#pragma unroll
        for (int j = 0; j < 4; ++j)
            x[j] = lat[(size_t)(tokb + t0 + i + j) * DC + lane];
#pragma unroll
        for (int j = 0; j < 4; ++j) {
            float d = q[j] - x[j];
            lsum = fmaf(d, d, lsum);
            quant_out[(size_t)(tokb + t0 + i + j) * DC + lane] = q[j];
        }
    }

#pragma unroll
    for (int o = 32; o > 0; o >>= 1) lsum += __shfl_down(lsum, o);
    if (lane == 0) wred[wv] = lsum;
    __syncthreads();
    if (tid == 0) atomicAdd(sum_sq, wred[0] + wred[1] + wred[2] + wred[3]);
}

// grid (NCODE, NTOK/DWCHUNK); skew-proof (round-5 lesson: do not regrid).
__global__ __launch_bounds__(256)
void dw_kernel(const float* __restrict__ lat, const int* __restrict__ bucket,
               const int* __restrict__ offs, const unsigned int* __restrict__ counts,
               float* __restrict__ dw)
{
    __shared__ float sred[4][64];
    const int code = blockIdx.x;
    const int n = (int)counts[code];
    const int start = blockIdx.y * DWCHUNK;
    if (start >= n) return;
    const int cnt = min(n - start, DWCHUNK);
    const int base = offs[code] + start;
    const int lane = threadIdx.x & 63, wave = threadIdx.x >> 6;

    float s0 = 0.f, s1 = 0.f, s2 = 0.f, s3 = 0.f;
    int i = wave;
    for (; i + 12 < cnt; i += 16) {
        int t0 = bucket[base + i];
        int t1 = bucket[base + i + 4];
        int t2 = bucket[base + i + 8];
        int t3 = bucket[base + i + 12];
        s0 += lat[(size_t)t0 * DC + lane];
        s1 += lat[(size_t)t1 * DC + lane];
        s2 += lat[(size_t)t2 * DC + lane];
        s3 += lat[(size_t)t3 * DC + lane];
    }
    for (; i < cnt; i += 4)
        s0 += lat[(size_t)bucket[base + i] * DC + lane];

    sred[wave][lane] = (s0 + s1) + (s2 + s3);
    __syncthreads();
    if (threadIdx.x < 64) {
        float tot = sred[0][lane] + sred[1][lane] + sred[2][lane] + sred[3][lane];
        atomicAdd(&dw[(size_t)lane * NCODE + code], tot);
    }
}

// ======================= finalize =======================
__global__ __launch_bounds__(1024)
void finalize_kernel(const unsigned int* __restrict__ counts,
                     const float* __restrict__ dw,
                     const float* __restrict__ ema_ch,
                     const float* __restrict__ ema_dw,
                     const float* __restrict__ sum_sq,
                     float* __restrict__ out_loss, float* __restrict__ out_perp,
                     float* __restrict__ out_newemb)
{
    __shared__ float sred[1024];
    const int k = threadIdx.x;
    const float debias = (float)(1.0 - pow(0.99, 1001.0));
    float cnt = (float)counts[k];
    float cs  = (ema_ch[k] * 0.99f + cnt * 0.01f) / debias;

    sred[k] = cs; __syncthreads();
    for (int s = 512; s > 0; s >>= 1) { if (k < s) sred[k] += sred[k + s]; __syncthreads(); }
    float n = sred[0];
    __syncthreads();

    float p = cnt / 98304.0f;
    sred[k] = p * logf(p + 1e-10f);
    __syncthreads();
    for (int s = 512; s > 0; s >>= 1) { if (k < s) sred[k] += sred[k + s]; __syncthreads(); }
    if (k == 0) {
        out_perp[0] = expf(-sred[0]);
        out_loss[0] = 0.25f * sum_sq[0] / 6291456.0f;
    }

    float stable = (cs + 1e-5f) / (n + 1024.0f * 1e-5f) * n;
#pragma unroll
    for (int c = 0; c < 64; ++c) {
        size_t o = (size_t)c * 1024 + k;
        out_newemb[o] = ((ema_dw[o] * 0.99f + dw[o] * 0.01f) / debias) / stable;
    }
}

extern "C" void kernel_launch(void* const* d_in, const int* in_sizes, int n_in,
                              void* d_out, int out_size, void* d_ws, size_t ws_size,
                              hipStream_t stream)
{
    (void)in_sizes; (void)n_in; (void)out_size; (void)ws_size;
    const float* states = (const float*)d_in[0];
    const float* w_se   = (const float*)d_in[1];
    const float* b_se   = (const float*)d_in[2];
    const float* w0     = (const float*)d_in[3];
    const float* b0     = (const float*)d_in[4];
    const float* w1     = (const float*)d_in[5];
    const float* b1     = (const float*)d_in[6];
    const float* w2     = (const float*)d_in[7];
    const float* b2     = (const float*)d_in[8];
    const float* emb    = (const float*)d_in[9];
    const float* ema_ch = (const float*)d_in[10];
    const float* ema_dw = (const float*)d_in[11];

    float* out        = (float*)d_out;
    float* q_out      = out;                    // 6291456
    float* loss_out   = out + 6291456;          // 1
    float* perp_out   = out + 6291457;          // 1
    float* idx_out    = out + 6291458;          // 98304
    float* newemb_out = out + 6389762;          // 65536

    // ---- workspace layout (zeroed prefix first) ----
    char* ws = (char*)d_ws;
    size_t o = 0;
    unsigned int* counts  = (unsigned int*)(ws + o); o += 4096;
    float*        sumsq   = (float*)(ws + o);        o += 256;
    float*        dwb     = (float*)(ws + o);        o += (size_t)DC * NCODE * 4;  // zeroed
    const size_t ZERO_BYTES = o;
    int*          offs    = (int*)(ws + o);          o += 4096;
    int*          codes   = (int*)(ws + o);          o += (size_t)NTOK * 4;
    int*          crank   = (int*)(ws + o);          o += (size_t)NTOK * 4;
    int*          bucket  = (int*)(ws + o);          o += (size_t)NTOK * 4;
    float*        e2b     = (float*)(ws + o);        o += 4096;
    unsigned int* hist2d  = (unsigned int*)(ws + o); o += (size_t)HBLK * NCODE * 4;
    int*          base2d  = (int*)(ws + o);          o += (size_t)HBLK * NCODE * 4;
    _Float16*     ebh     = (_Float16*)(ws + o);     o += (size_t)NCODE * DC * 2;
    _Float16*     ebl     = (_Float16*)(ws + o);     o += (size_t)NCODE * DC * 2;
    float*        embT    = (float*)(ws + o);        o += (size_t)NCODE * DC * 4;
    _Float16*     wseh    = (_Float16*)(ws + o);     o += (size_t)DIN * DE * 2;
    _Float16*     wsel    = (_Float16*)(ws + o);     o += (size_t)DIN * DE * 2;
    _Float16*     w0h     = (_Float16*)(ws + o);     o += (size_t)DE * DH * 2;
    _Float16*     w0l     = (_Float16*)(ws + o);     o += (size_t)DE * DH * 2;
    _Float16*     w1h     = (_Float16*)(ws + o);     o += (size_t)DH * DH * 2;
    _Float16*     w1l     = (_Float16*)(ws + o);     o += (size_t)DH * DH * 2;
    _Float16*     w2h     = (_Float16*)(ws + o);     o += (size_t)DH * DC * 2;
    _Float16*     w2l     = (_Float16*)(ws + o);     o += (size_t)DH * DC * 2;
    _Float16*     bufAh   = (_Float16*)(ws + o);     o += (size_t)CHUNK * DE * 2;
    _Float16*     bufAl   = (_Float16*)(ws + o);     o += (size_t)CHUNK * DE * 2;
    _Float16*     bufBh   = (_Float16*)(ws + o);     o += (size_t)CHUNK * DH * 2;
    _Float16*     bufBl   = (_Float16*)(ws + o);     o += (size_t)CHUNK * DH * 2;
    float*        lat     = (float*)(ws + o);        o += (size_t)NTOK * DC * 4;

    hipMemsetAsync(d_ws, 0, ZERO_BYTES, stream);

    // weight/codebook prep (tiny)
    transpose_split_fm<<<dim3((DIN * DE + 255) / 256), dim3(256), 0, stream>>>(w_se, wseh, wsel, DIN, DE);
    transpose_split_fm<<<dim3((DE * DH + 255) / 256), dim3(256), 0, stream>>>(w0, w0h, w0l, DE, DH);
    transpose_split_fm<<<dim3((DH * DH + 255) / 256), dim3(256), 0, stream>>>(w1, w1h, w1l, DH, DH);
    transpose_split_fm<<<dim3((DH * DC + 255) / 256), dim3(256), 0, stream>>>(w2, w2h, w2l, DH, DC);
    prep_emb<<<dim3(256), dim3(256), 0, stream>>>(emb, ebh, ebl, embT);
    e2_kernel<<<dim3(4), dim3(256), 0, stream>>>(emb, e2b);

    dim3 blk(256);
    const int MBLK = CHUNK / 128;
    for (int c = 0; c < NTOK / CHUNK; ++c) {
        size_t off = (size_t)c * CHUNK;
        gemm_fm<128, 32, false, true><<<dim3(DE / 128, MBLK), blk, 0, stream>>>(
            states + off * DIN, nullptr, wseh, wsel, b_se, bufAh, bufAl, CHUNK, DE, DIN);
        gemm_fm<64, 64, true, true><<<dim3(DH / 64, MBLK), blk, 0, stream>>>(
            bufAh, bufAl, w0h, w0l, b0, bufBh, bufBl, CHUNK, DH, DE);
        gemm_fm<64, 64, true, true><<<dim3(DH / 64, MBLK), blk, 0, stream>>>(
            bufBh, bufBl, w1h, w1l, b1, bufAh, bufAl, CHUNK, DH, DH);
        gemm_fm<64, 64, true, false><<<dim3(DC / 64, MBLK), blk, 0, stream>>>(
            bufAh, bufAl, w2h, w2l, b2, lat + off * DC, nullptr, CHUNK, DC, DH);
    }

    vq_dist_kernel<<<dim3(NTOK / 128), blk, 0, stream>>>(
        lat, ebh, ebl, e2b, idx_out, codes);

    vq_quant_kernel<<<dim3(NTOK / 256), blk, 0, stream>>>(
        lat, embT, codes, q_out, sumsq);

    hist_rank_kernel<<<dim3(HBLK), blk, 0, stream>>>(codes, crank, hist2d);
    scan_kernel<<<dim3(1), dim3(1024), 0, stream>>>(hist2d, counts, offs, base2d);
    scatter_kernel<<<dim3(HBLK), blk, 0, stream>>>(codes, crank, base2d, bucket);
    dw_kernel<<<dim3(NCODE, NTOK / DWCHUNK), blk, 0, stream>>>(lat, bucket, offs, counts, dwb);

    finalize_kernel<<<dim3(1), dim3(1024), 0, stream>>>(counts, dwb, ema_ch, ema_dw, sumsq,
                                                        loss_out, perp_out, newemb_out);
}

// Round 14
// 820.613 us; speedup vs baseline: 1.0960x; 1.0960x over previous
//
#include <hip/hip_runtime.h>
#include <hip/hip_bf16.h>
#include <math.h>

// Problem dims (fixed by reference)
#define NTOK 98304      // 32768 * 3
#define DIN  256
#define DE   512
#define DH   512
#define DC   64
#define NCODE 1024
#define CHUNK 49152     // tokens per pipeline chunk (2 chunks)
#define DWCHUNK 1024    // tokens per dw block (skew-proof: hot code gets 96 blocks)
#define HBLK 96         // histogram blocks (1024 tokens each)

typedef _Float16 half8 __attribute__((ext_vector_type(8)));
typedef float f32x4 __attribute__((ext_vector_type(4)));

// fast gelu (tanh approximation): gelu(x) = x * sigmoid(2*k0*(x + k1 x^3)).
// HW exp2 + rcp (round 12: −9 µs/dispatch, absmax unchanged).
__device__ __forceinline__ float gelu_f(float x) {
    const float k1 = 0.044715f;
    const float C = -(2.0f * 1.4426950408889634f * 0.7978845608028654f);
    float q = x * x;
    float r = fmaf(k1, q, 1.0f);
    float t = x * r * C;
    float e = __builtin_amdgcn_exp2f(t);
    float s = __builtin_amdgcn_rcpf(e + 1.0f);
    return x * s;
}

// async global->LDS, 16B per lane (LDS dest = wave-uniform base + lane*16)
__device__ __forceinline__ void gload_lds16(const _Float16* g, _Float16* l) {
    __builtin_amdgcn_global_load_lds(
        (const __attribute__((address_space(1))) void*)g,
        (__attribute__((address_space(3))) void*)l, 16, 0, 0);
}

__device__ __forceinline__ void raw_barrier() {
    asm volatile("s_barrier" ::: "memory");
}
__device__ __forceinline__ void lgkm0_barrier() {
    asm volatile("s_waitcnt lgkmcnt(0)" ::: "memory");
    asm volatile("s_barrier" ::: "memory");
}

// W[K][N] fp32 -> fragment-major hi/lo fp16 planes: P[(k>>3)*N*8 + n*8 + (k&7)]
__global__ __launch_bounds__(256)
void transpose_split_fm(const float* __restrict__ W, _Float16* __restrict__ Bh,
                        _Float16* __restrict__ Bl, int K, int N)
{
    int e = blockIdx.x * 256 + threadIdx.x;
    if (e >= K * N) return;
    int k = e / N, n = e % N;
    float v = W[e];
    _Float16 h = (_Float16)v;
    _Float16 l = (_Float16)(v - (float)h);
    size_t o = ((size_t)(k >> 3) * N + n) * 8 + (k & 7);
    Bh[o] = h; Bl[o] = l;
}

// ======================= MLP GEMM (fp16x3 MFMA, global_load_lds staging) =====
// Round-12 proven configuration (BN=128/BK=32, 32KB LDS, 2 syncthreads/K-step,
// XCD swizzle). Round-13 BK=64/BN=64 regressed (+9%): BN=64 halves A reuse ->
// staged bytes/FLOP +50%; tile aspect dominates barrier count in this
// template. 883 TF here == 97% of this structure's documented ceiling.
template<int BN, bool A_FM, bool EMIT_FM>
__global__ __launch_bounds__(256, 2)
void gemm_fm(const void* __restrict__ A0, const void* __restrict__ A1,
             const _Float16* __restrict__ Bhp, const _Float16* __restrict__ Blp,
             const float* __restrict__ bias,
             void* __restrict__ C0, void* __restrict__ C1,
             int M, int N, int K)
{
    constexpr int BM = 128;
    constexpr int WGM = (BN == 128) ? 2 : 4;
    constexpr int WAVE_M = BM / WGM;
    constexpr int MT = WAVE_M / 16;
    constexpr int NT = 4;
    constexpr int NSHIFT = (BN == 128) ? 7 : 6;
    constexpr int BCALLS = (BN * 4) / 256;     // 16B-chunks per plane / 256 thr

    __shared__ __align__(16) _Float16 As[2][4][BM][8];   // 16 KB
    __shared__ __align__(16) _Float16 Bs[2][4][BN][8];   // 16 or 8 KB

    const int tid  = threadIdx.x;
    const int lane = tid & 63, wid = tid >> 6;
    const int lm   = lane & 15, quad = lane >> 4;
    const int wave_m = (BN == 128) ? (wid & 1) * 64 : wid * 32;
    const int wave_n = (BN == 128) ? (wid >> 1) * 64 : 0;

    // ---- XCD-aware swizzle (bijective; requires gridDim.y % 8 == 0) ----
    int bx = blockIdx.x, by = blockIdx.y;
    if (gridDim.x == 4 && (gridDim.y & 7) == 0) {
        int L = by * 4 + bx;          // linear dispatch id (x-fastest)
        int c = L & 7, w = L >> 3;
        bx = w & 3;                   // member (N-block) 0..3
        by = (w >> 2) * 8 + c;        // A-panel
    }
    const int m0 = by * BM, n0 = bx * BN;

    f32x4 acc[MT][NT];
#pragma unroll
    for (int mi = 0; mi < MT; ++mi)
#pragma unroll
        for (int ni = 0; ni < NT; ++ni) acc[mi][ni] = (f32x4)(0.f);

    for (int k0 = 0; k0 < K; k0 += 32) {
        const int kb0 = k0 >> 3;

        // ---- stage A ----
        if (A_FM) {
            const _Float16* ap[2] = {(const _Float16*)A0, (const _Float16*)A1};
#pragma unroll
            for (int p = 0; p < 2; ++p)
#pragma unroll
                for (int j = 0; j < 2; ++j) {
                    int e  = j * 256 + tid;
                    int kb = e >> 7, tk = e & 127;
                    const _Float16* src = ap[p] + ((size_t)(kb0 + kb) * M + m0 + tk) * 8;
                    int eb = j * 256 + (tid & ~63);
                    gload_lds16(src, &As[p][eb >> 7][eb & 127][0]);
                }
        } else {
            // fp32 A (states): reg-stage + hi/lo split
            const float* A = (const float*)A0;
#pragma unroll
            for (int i = 0; i < 4; ++i) {
                int s = tid + i * 256;
                int row = s >> 3, kc = (s & 7) * 4;
                int kb = kc >> 3, off = kc & 7;
                float4 v = *(const float4*)(A + (size_t)(m0 + row) * K + k0 + kc);
                float vv[4] = {v.x, v.y, v.z, v.w};
                unsigned short h[4], l[4];
#pragma unroll
                for (int j = 0; j < 4; ++j) {
                    _Float16 hh = (_Float16)vv[j];
                    _Float16 ll = (_Float16)(vv[j] - (float)hh);
                    h[j] = __builtin_bit_cast(unsigned short, hh);
                    l[j] = __builtin_bit_cast(unsigned short, ll);
                }
                uint2 ph, pl;
                ph.x = (unsigned int)h[0] | ((unsigned int)h[1] << 16);
                ph.y = (unsigned int)h[2] | ((unsigned int)h[3] << 16);
                pl.x = (unsigned int)l[0] | ((unsigned int)l[1] << 16);
                pl.y = (unsigned int)l[2] | ((unsigned int)l[3] << 16);
                *(uint2*)&As[0][kb][row][off] = ph;
                *(uint2*)&As[1][kb][row][off] = pl;
            }
        }

        // ---- stage B (always fragment-major planes) ----
        {
            const _Float16* bp[2] = {Bhp, Blp};
#pragma unroll
            for (int p = 0; p < 2; ++p)
#pragma unroll
                for (int j = 0; j < BCALLS; ++j) {
                    int e  = j * 256 + tid;
                    int kb = e >> NSHIFT, n = e & (BN - 1);
                    const _Float16* src = bp[p] + ((size_t)(kb0 + kb) * N + n0 + n) * 8;
                    int eb = j * 256 + (tid & ~63);
                    gload_lds16(src, &Bs[p][eb >> NSHIFT][eb & (BN - 1)][0]);
                }
        }
        __syncthreads();

        half8 ahf[MT], alf[MT], bhf[NT], blf[NT];
#pragma unroll
        for (int mi = 0; mi < MT; ++mi) {
            int r = wave_m + mi * 16 + lm;
            ahf[mi] = *(const half8*)&As[0][quad][r][0];
            alf[mi] = *(const half8*)&As[1][quad][r][0];
        }
#pragma unroll
        for (int ni = 0; ni < NT; ++ni) {
            int c = wave_n + ni * 16 + lm;
            bhf[ni] = *(const half8*)&Bs[0][quad][c][0];
            blf[ni] = *(const half8*)&Bs[1][quad][c][0];
        }
#pragma unroll
        for (int mi = 0; mi < MT; ++mi)
#pragma unroll
            for (int ni = 0; ni < NT; ++ni) {
                acc[mi][ni] = __builtin_amdgcn_mfma_f32_16x16x32_f16(ahf[mi], bhf[ni], acc[mi][ni], 0, 0, 0);
                acc[mi][ni] = __builtin_amdgcn_mfma_f32_16x16x32_f16(ahf[mi], blf[ni], acc[mi][ni], 0, 0, 0);
                acc[mi][ni] = __builtin_amdgcn_mfma_f32_16x16x32_f16(alf[mi], bhf[ni], acc[mi][ni], 0, 0, 0);
            }
        __syncthreads();
    }

#pragma unroll
    for (int ni = 0; ni < NT; ++ni) {
        int col = n0 + wave_n + ni * 16 + lm;
        float bv = bias[col];
        size_t slab = EMIT_FM ? ((size_t)(col >> 3) * M * 8 + (col & 7)) : 0;
#pragma unroll
        for (int mi = 0; mi < MT; ++mi) {
            int rowbase = m0 + wave_m + mi * 16 + quad * 4;
#pragma unroll
            for (int r = 0; r < 4; ++r) {
                float g = gelu_f(acc[mi][ni][r] + bv);
                if (EMIT_FM) {
                    _Float16 hh = (_Float16)g;
                    _Float16 ll = (_Float16)(g - (float)hh);
                    size_t oo = slab + (size_t)(rowbase + r) * 8;
                    ((_Float16*)C0)[oo] = hh;
                    ((_Float16*)C1)[oo] = ll;
                } else {
                    ((float*)C0)[(size_t)(rowbase + r) * N + col] = g;
                }
            }
        }
    }
}

// ======================= VQ prep =======================
__global__ __launch_bounds__(256)
void prep_emb(const float* __restrict__ emb, _Float16* __restrict__ ebh,
              _Float16* __restrict__ ebl, float* __restrict__ embT)
{
    int e = blockIdx.x * 256 + threadIdx.x;   // 65536
    int c = e >> 10, n = e & 1023;
    float v = emb[e];
    _Float16 h = (_Float16)v;
    _Float16 l = (_Float16)(v - (float)h);
    ebh[(size_t)n * DC + c] = h;
    ebl[(size_t)n * DC + c] = l;
    embT[(size_t)n * DC + c] = v;
}

__global__ __launch_bounds__(256)
void e2_kernel(const float* __restrict__ emb, float* __restrict__ e2)
{
    int n = blockIdx.x * 256 + threadIdx.x;   // 1024
    float s = 0.f;
#pragma unroll
    for (int c = 0; c < DC; ++c) { float e = emb[(size_t)c * NCODE + n]; s = fmaf(e, e, s); }
    e2[n] = s;
}

// ======================= VQ distance+argmin+quantize (fused, NO count atomics)
// Round-14: vq_quant fused back as a post-argmin phase (sidx via LDS) — the
// round-6/7 split existed only for ablation. Quant gathers exact fp32 embT.
__global__ __launch_bounds__(256, 2)
void vq_dist_kernel(const float* __restrict__ lat,
                    const _Float16* __restrict__ ebh, const _Float16* __restrict__ ebl,
                    const float* __restrict__ e2, const float* __restrict__ embT,
                    float* __restrict__ encidx_out, int* __restrict__ codes_out,
                    float* __restrict__ quant_out, float* __restrict__ sum_sq)
{
    __shared__ __align__(16) char Bt[16384];   // staged tile: hi 8KB + lo 8KB (swizzled)
    __shared__ float e2s[NCODE];               // 4096 B
    __shared__ int sidx[128];
    __shared__ float wred[4];

    const int tid = threadIdx.x, lane = tid & 63, wave = tid >> 6;
    const int lm = lane & 15, quad = lane >> 4;
    const int tok0 = blockIdx.x * 128;

    // ---- A fragments: load directly from lat (fp32), split to hi/lo fp16 ----
    half8 ah[2][2], al[2][2];   // [mt][ks]
#pragma unroll
    for (int mt = 0; mt < 2; ++mt)
#pragma unroll
        for (int ks = 0; ks < 2; ++ks) {
            const float* ap = lat + (size_t)(tok0 + wave * 32 + mt * 16 + lm) * DC + ks * 32 + quad * 8;
            float4 v0 = *(const float4*)ap;
            float4 v1 = *(const float4*)(ap + 4);
            float vv[8] = {v0.x, v0.y, v0.z, v0.w, v1.x, v1.y, v1.z, v1.w};
            half8 hh, ll;
#pragma unroll
            for (int j = 0; j < 8; ++j) {
                _Float16 h = (_Float16)vv[j];
                hh[j] = h;
                ll[j] = (_Float16)(vv[j] - (float)h);
            }
            ah[mt][ks] = hh;
            al[mt][ks] = ll;
        }

    // e2 table -> LDS
#pragma unroll
    for (int i = 0; i < 4; ++i) { int k = tid + i * 256; e2s[k] = e2[k]; }

    const _Float16* srcbase[4];
    int ldsoff[4];
#pragma unroll
    for (int k = 0; k < 4; ++k) {
        int S = tid + (k << 8);
        int r = (S & 511) >> 3, c16 = S & 7;
        srcbase[k] = ((S < 512) ? ebh : ebl) + (r << 6) + (c16 << 3);
        ldsoff[k] = ((S >> 9) << 13) + (r << 7) + ((c16 ^ (r & 7)) << 4);
    }

    uint4 stg[4];
#pragma unroll
    for (int k = 0; k < 4; ++k) stg[k] = *(const uint4*)(srcbase[k]);           // tile 0
#pragma unroll
    for (int k = 0; k < 4; ++k) *(uint4*)(Bt + ldsoff[k]) = stg[k];
#pragma unroll
    for (int k = 0; k < 4; ++k) stg[k] = *(const uint4*)(srcbase[k] + 4096);    // tile 1
    lgkm0_barrier();

    const char* Bhi = (const char*)Bt;
    const char* Blo = (const char*)Bt + 8192;

    f32x4 acc[2][4];
    float bd[2][4]; int bi[2][4];
#pragma unroll
    for (int mt = 0; mt < 2; ++mt)
#pragma unroll
        for (int r = 0; r < 4; ++r) { bd[mt][r] = INFINITY; bi[mt][r] = 0; }

    for (int t = 0; t < 16; ++t) {
        const int k0 = t * 64;
#pragma unroll
        for (int mt = 0; mt < 2; ++mt)
#pragma unroll
            for (int ni = 0; ni < 4; ++ni) acc[mt][ni] = (f32x4)(0.f);

#pragma unroll
        for (int ks = 0; ks < 2; ++ks) {
            half8 bh[4], bl[4];
#pragma unroll
            for (int ni = 0; ni < 4; ++ni) {
                int cl = ni * 16 + lm;
                int sw = ((ks * 4 + quad) ^ (cl & 7)) << 4;
                bh[ni] = *(const half8*)(Bhi + (cl << 7) + sw);
                bl[ni] = *(const half8*)(Blo + (cl << 7) + sw);
            }
#pragma unroll
            for (int ni = 0; ni < 4; ++ni)
#pragma unroll
                for (int mt = 0; mt < 2; ++mt) {
                    acc[mt][ni] = __builtin_amdgcn_mfma_f32_16x16x32_f16(ah[mt][ks], bh[ni], acc[mt][ni], 0, 0, 0);
                    acc[mt][ni] = __builtin_amdgcn_mfma_f32_16x16x32_f16(ah[mt][ks], bl[ni], acc[mt][ni], 0, 0, 0);
                    acc[mt][ni] = __builtin_amdgcn_mfma_f32_16x16x32_f16(al[mt][ks], bh[ni], acc[mt][ni], 0, 0, 0);
                    acc[mt][ni] = __builtin_amdgcn_mfma_f32_16x16x32_f16(al[mt][ks], bl[ni], acc[mt][ni], 0, 0, 0);
                }
        }

#pragma unroll
        for (int ni = 0; ni < 4; ++ni) {
            int code = k0 + ni * 16 + lm;
            float ee = e2s[code];
#pragma unroll
            for (int mt = 0; mt < 2; ++mt)
#pragma unroll
                for (int r = 0; r < 4; ++r) {
                    float d = ee - 2.f * acc[mt][ni][r];
                    if (d < bd[mt][r]) { bd[mt][r] = d; bi[mt][r] = code; }
                }
        }

        raw_barrier();
        if (t < 15) {
#pragma unroll
            for (int k = 0; k < 4; ++k) *(uint4*)(Bt + ldsoff[k]) = stg[k];    // tile t+1
            if (t < 14) {
#pragma unroll
                for (int k = 0; k < 4; ++k)
                    stg[k] = *(const uint4*)(srcbase[k] + (size_t)(t + 2) * 4096);
            }
            lgkm0_barrier();
        }
    }

    // argmin across the 16 lanes of each quad-group via shfl_xor
#pragma unroll
    for (int mt = 0; mt < 2; ++mt)
#pragma unroll
        for (int r = 0; r < 4; ++r) {
            float d = bd[mt][r]; int i0 = bi[mt][r];
#pragma unroll
            for (int off = 1; off < 16; off <<= 1) {
                float od = __shfl_xor(d, off, 64);
                int   oi = __shfl_xor(i0, off, 64);
                if (od < d || (od == d && oi < i0)) { d = od; i0 = oi; }
            }
            if (lm == 0) {
                int tok = wave * 32 + mt * 16 + quad * 4 + r;
                sidx[tok] = i0;
                encidx_out[tok0 + tok] = (float)i0;
                codes_out[tok0 + tok] = i0;
            }
        }
    __syncthreads();

    // ---- quantize + e_latent_loss (exact fp32 embT gather) ----
    const int t2 = tid >> 1;        // token 0..127
    const int g  = tid & 1;         // half of the 64 dims
    const int code = sidx[t2];
    float lsum = 0.f;
#pragma unroll
    for (int q = 0; q < 4; ++q) {
        int c0 = g * 32 + q * 8;
        const size_t tb = (size_t)(tok0 + t2) * DC + c0;
        float4 x0 = *(const float4*)(lat + tb);
        float4 x1 = *(const float4*)(lat + tb + 4);
        float4 e0 = *(const float4*)(embT + (size_t)code * DC + c0);
        float4 e1 = *(const float4*)(embT + (size_t)code * DC + c0 + 4);
        float xx[8] = {x0.x, x0.y, x0.z, x0.w, x1.x, x1.y, x1.z, x1.w};
        float qq[8] = {e0.x, e0.y, e0.z, e0.w, e1.x, e1.y, e1.z, e1.w};
#pragma unroll
        for (int j = 0; j < 8; ++j) {
            float d = qq[j] - xx[j];
            lsum = fmaf(d, d, lsum);
        }
        *(float4*)(quant_out + tb) = e0;
        *(float4*)(quant_out + tb + 4) = e1;
    }
#pragma unroll
    for (int o = 32; o > 0; o >>= 1) lsum += __shfl_down(lsum, o);
    if (lane == 0) wred[wave] = lsum;
    __syncthreads();
    if (tid == 0) atomicAdd(sum_sq, wred[0] + wred[1] + wred[2] + wred[3]);
}

// ======================= histogram + rank (non-atomic counts) ================
__global__ __launch_bounds__(256)
void hist_rank_kernel(const int* __restrict__ codes, int* __restrict__ crank,
                      unsigned int* __restrict__ hist2d)
{
    __shared__ unsigned int hist[NCODE];
    const int tid = threadIdx.x, b = blockIdx.x;
#pragma unroll
    for (int j = 0; j < 4; ++j) hist[tid + j * 256] = 0;
    __syncthreads();
#pragma unroll
    for (int j = 0; j < 4; ++j) {
        int t = b * 1024 + j * 256 + tid;
        int c = codes[t];
        crank[t] = (int)atomicAdd(&hist[c], 1u);   // LDS atomic
    }
    __syncthreads();
#pragma unroll
    for (int j = 0; j < 4; ++j) {
        int k = tid + j * 256;
        hist2d[(size_t)b * NCODE + k] = hist[k];
    }
}

// ======================= scan: counts, offs, per-block bases =================
__global__ __launch_bounds__(1024)
void scan_kernel(const unsigned int* __restrict__ hist2d,
                 unsigned int* __restrict__ counts, int* __restrict__ offs,
                 int* __restrict__ base2d)
{
    __shared__ int s[1024];
    const int t = threadIdx.x;
    int v = 0;
    for (int b = 0; b < HBLK; ++b) v += (int)hist2d[(size_t)b * NCODE + t];
    counts[t] = (unsigned int)v;
    s[t] = v; __syncthreads();
    for (int d = 1; d < 1024; d <<= 1) {
        int x = (t >= d) ? s[t - d] : 0;
        __syncthreads();
        s[t] += x;
        __syncthreads();
    }
    int run = s[t] - v;          // exclusive prefix
    offs[t] = run;
    for (int b = 0; b < HBLK; ++b) {
        base2d[(size_t)b * NCODE + t] = run;
        run += (int)hist2d[(size_t)b * NCODE + t];
    }
}

// ======================= scatter (atomic-free) ===============================
__global__ __launch_bounds__(256)
void scatter_kernel(const int* __restrict__ codes, const int* __restrict__ crank,
                    const int* __restrict__ base2d, int* __restrict__ bucket)
{
    const int tid = threadIdx.x, b = blockIdx.x;
#pragma unroll
    for (int j = 0; j < 4; ++j) {
        int t = b * 1024 + j * 256 + tid;
        int c = codes[t];
        bucket[base2d[(size_t)b * NCODE + c] + crank[t]] = t;
    }
}

// grid (NCODE, NTOK/DWCHUNK); skew-proof (round-5 lesson: do not regrid).
__global__ __launch_bounds__(256)
void dw_kernel(const float* __restrict__ lat, const int* __restrict__ bucket,
               const int* __restrict__ offs, const unsigned int* __restrict__ counts,
               float* __restrict__ dw)
{
    __shared__ float sred[4][64];
    const int code = blockIdx.x;
    const int n = (int)counts[code];
    const int start = blockIdx.y * DWCHUNK;
    if (start >= n) return;
    const int cnt = min(n - start, DWCHUNK);
    const int base = offs[code] + start;
    const int lane = threadIdx.x & 63, wave = threadIdx.x >> 6;

    float s0 = 0.f, s1 = 0.f, s2 = 0.f, s3 = 0.f;
    int i = wave;
    for (; i + 12 < cnt; i += 16) {
        int t0 = bucket[base + i];
        int t1 = bucket[base + i + 4];
        int t2 = bucket[base + i + 8];
        int t3 = bucket[base + i + 12];
        s0 += lat[(size_t)t0 * DC + lane];
        s1 += lat[(size_t)t1 * DC + lane];
        s2 += lat[(size_t)t2 * DC + lane];
        s3 += lat[(size_t)t3 * DC + lane];
    }
    for (; i < cnt; i += 4)
        s0 += lat[(size_t)bucket[base + i] * DC + lane];

    sred[wave][lane] = (s0 + s1) + (s2 + s3);
    __syncthreads();
    if (threadIdx.x < 64) {
        float tot = sred[0][lane] + sred[1][lane] + sred[2][lane] + sred[3][lane];
        atomicAdd(&dw[(size_t)lane * NCODE + code], tot);
    }
}

// ======================= finalize =======================
__global__ __launch_bounds__(1024)
void finalize_kernel(const unsigned int* __restrict__ counts,
                     const float* __restrict__ dw,
                     const float* __restrict__ ema_ch,
                     const float* __restrict__ ema_dw,
                     const float* __restrict__ sum_sq,
                     float* __restrict__ out_loss, float* __restrict__ out_perp,
                     float* __restrict__ out_newemb)
{
    __shared__ float sred[1024];
    const int k = threadIdx.x;
    const float debias = (float)(1.0 - pow(0.99, 1001.0));
    float cnt = (float)counts[k];
    float cs  = (ema_ch[k] * 0.99f + cnt * 0.01f) / debias;

    sred[k] = cs; __syncthreads();
    for (int s = 512; s > 0; s >>= 1) { if (k < s) sred[k] += sred[k + s]; __syncthreads(); }
    float n = sred[0];
    __syncthreads();

    float p = cnt / 98304.0f;
    sred[k] = p * logf(p + 1e-10f);
    __syncthreads();
    for (int s = 512; s > 0; s >>= 1) { if (k < s) sred[k] += sred[k + s]; __syncthreads(); }
    if (k == 0) {
        out_perp[0] = expf(-sred[0]);
        out_loss[0] = 0.25f * sum_sq[0] / 6291456.0f;
    }

    float stable = (cs + 1e-5f) / (n + 1024.0f * 1e-5f) * n;
#pragma unroll
    for (int c = 0; c < 64; ++c) {
        size_t o = (size_t)c * 1024 + k;
        out_newemb[o] = ((ema_dw[o] * 0.99f + dw[o] * 0.01f) / debias) / stable;
    }
}

extern "C" void kernel_launch(void* const* d_in, const int* in_sizes, int n_in,
                              void* d_out, int out_size, void* d_ws, size_t ws_size,
                              hipStream_t stream)
{
    (void)in_sizes; (void)n_in; (void)out_size; (void)ws_size;
    const float* states = (const float*)d_in[0];
    const float* w_se   = (const float*)d_in[1];
    const float* b_se   = (const float*)d_in[2];
    const float* w0     = (const float*)d_in[3];
    const float* b0     = (const float*)d_in[4];
    const float* w1     = (const float*)d_in[5];
    const float* b1     = (const float*)d_in[6];
    const float* w2     = (const float*)d_in[7];
    const float* b2     = (const float*)d_in[8];
    const float* emb    = (const float*)d_in[9];
    const float* ema_ch = (const float*)d_in[10];
    const float* ema_dw = (const float*)d_in[11];

    float* out        = (float*)d_out;
    float* q_out      = out;                    // 6291456
    float* loss_out   = out + 6291456;          // 1
    float* perp_out   = out + 6291457;          // 1
    float* idx_out    = out + 6291458;          // 98304
    float* newemb_out = out + 6389762;          // 65536

    // ---- workspace layout (zeroed prefix first) ----
    char* ws = (char*)d_ws;
    size_t o = 0;
    unsigned int* counts  = (unsigned int*)(ws + o); o += 4096;
    float*        sumsq   = (float*)(ws + o);        o += 256;
    float*        dwb     = (float*)(ws + o);        o += (size_t)DC * NCODE * 4;  // zeroed
    const size_t ZERO_BYTES = o;
    int*          offs    = (int*)(ws + o);          o += 4096;
    int*          codes   = (int*)(ws + o);          o += (size_t)NTOK * 4;
    int*          crank   = (int*)(ws + o);          o += (size_t)NTOK * 4;
    int*          bucket  = (int*)(ws + o);          o += (size_t)NTOK * 4;
    float*        e2b     = (float*)(ws + o);        o += 4096;
    unsigned int* hist2d  = (unsigned int*)(ws + o); o += (size_t)HBLK * NCODE * 4;
    int*          base2d  = (int*)(ws + o);          o += (size_t)HBLK * NCODE * 4;
    _Float16*     ebh     = (_Float16*)(ws + o);     o += (size_t)NCODE * DC * 2;
    _Float16*     ebl     = (_Float16*)(ws + o);     o += (size_t)NCODE * DC * 2;
    float*        embT    = (float*)(ws + o);        o += (size_t)NCODE * DC * 4;
    _Float16*     wseh    = (_Float16*)(ws + o);     o += (size_t)DIN * DE * 2;
    _Float16*     wsel    = (_Float16*)(ws + o);     o += (size_t)DIN * DE * 2;
    _Float16*     w0h     = (_Float16*)(ws + o);     o += (size_t)DE * DH * 2;
    _Float16*     w0l     = (_Float16*)(ws + o);     o += (size_t)DE * DH * 2;
    _Float16*     w1h     = (_Float16*)(ws + o);     o += (size_t)DH * DH * 2;
    _Float16*     w1l     = (_Float16*)(ws + o);     o += (size_t)DH * DH * 2;
    _Float16*     w2h     = (_Float16*)(ws + o);     o += (size_t)DH * DC * 2;
    _Float16*     w2l     = (_Float16*)(ws + o);     o += (size_t)DH * DC * 2;
    _Float16*     bufAh   = (_Float16*)(ws + o);     o += (size_t)CHUNK * DE * 2;
    _Float16*     bufAl   = (_Float16*)(ws + o);     o += (size_t)CHUNK * DE * 2;
    _Float16*     bufBh   = (_Float16*)(ws + o);     o += (size_t)CHUNK * DH * 2;
    _Float16*     bufBl   = (_Float16*)(ws + o);     o += (size_t)CHUNK * DH * 2;
    float*        lat     = (float*)(ws + o);        o += (size_t)NTOK * DC * 4;

    hipMemsetAsync(d_ws, 0, ZERO_BYTES, stream);

    // weight/codebook prep (tiny)
    transpose_split_fm<<<dim3((DIN * DE + 255) / 256), dim3(256), 0, stream>>>(w_se, wseh, wsel, DIN, DE);
    transpose_split_fm<<<dim3((DE * DH + 255) / 256), dim3(256), 0, stream>>>(w0, w0h, w0l, DE, DH);
    transpose_split_fm<<<dim3((DH * DH + 255) / 256), dim3(256), 0, stream>>>(w1, w1h, w1l, DH, DH);
    transpose_split_fm<<<dim3((DH * DC + 255) / 256), dim3(256), 0, stream>>>(w2, w2h, w2l, DH, DC);
    prep_emb<<<dim3(256), dim3(256), 0, stream>>>(emb, ebh, ebl, embT);
    e2_kernel<<<dim3(4), dim3(256), 0, stream>>>(emb, e2b);

    dim3 blk(256);
    const int MBLK = CHUNK / 128;
    for (int c = 0; c < NTOK / CHUNK; ++c) {
        size_t off = (size_t)c * CHUNK;
        gemm_fm<128, false, true><<<dim3(DE / 128, MBLK), blk, 0, stream>>>(
            states + off * DIN, nullptr, wseh, wsel, b_se, bufAh, bufAl, CHUNK, DE, DIN);
        gemm_fm<128, true, true><<<dim3(DH / 128, MBLK), blk, 0, stream>>>(
            bufAh, bufAl, w0h, w0l, b0, bufBh, bufBl, CHUNK, DH, DE);
        gemm_fm<128, true, true><<<dim3(DH / 128, MBLK), blk, 0, stream>>>(
            bufBh, bufBl, w1h, w1l, b1, bufAh, bufAl, CHUNK, DH, DH);
        gemm_fm<64, true, false><<<dim3(1, MBLK), blk, 0, stream>>>(
            bufAh, bufAl, w2h, w2l, b2, lat + off * DC, nullptr, CHUNK, DC, DH);
    }

    vq_dist_kernel<<<dim3(NTOK / 128), blk, 0, stream>>>(
        lat, ebh, ebl, e2b, embT, idx_out, codes, q_out, sumsq);

    hist_rank_kernel<<<dim3(HBLK), blk, 0, stream>>>(codes, crank, hist2d);
    scan_kernel<<<dim3(1), dim3(1024), 0, stream>>>(hist2d, counts, offs, base2d);
    scatter_kernel<<<dim3(HBLK), blk, 0, stream>>>(codes, crank, base2d, bucket);
    dw_kernel<<<dim3(NCODE, NTOK / DWCHUNK), blk, 0, stream>>>(lat, bucket, offs, counts, dwb);

    finalize_kernel<<<dim3(1), dim3(1024), 0, stream>>>(counts, dwb, ema_ch, ema_dw, sumsq,
                                                        loss_out, perp_out, newemb_out);
}

// Round 15
// 807.181 us; speedup vs baseline: 1.1142x; 1.0166x over previous
//
#include <hip/hip_runtime.h>
#include <hip/hip_bf16.h>
#include <math.h>

// Problem dims (fixed by reference)
#define NTOK 98304      // 32768 * 3
#define DIN  256
#define DE   512
#define DH   512
#define DC   64
#define NCODE 1024
#define CHUNK 49152     // tokens per pipeline chunk (2 chunks)
#define DWCHUNK 1024    // tokens per dw block (skew-proof: hot code gets 96 blocks)
#define HBLK 96         // histogram blocks (1024 tokens each)

typedef _Float16 half8 __attribute__((ext_vector_type(8)));
typedef float f32x4 __attribute__((ext_vector_type(4)));

// fast gelu (tanh approximation): gelu(x) = x * sigmoid(2*k0*(x + k1 x^3)).
// HW exp2 + rcp (round 12: −9 µs/dispatch, absmax unchanged).
__device__ __forceinline__ float gelu_f(float x) {
    const float k1 = 0.044715f;
    const float C = -(2.0f * 1.4426950408889634f * 0.7978845608028654f);
    float q = x * x;
    float r = fmaf(k1, q, 1.0f);
    float t = x * r * C;
    float e = __builtin_amdgcn_exp2f(t);
    float s = __builtin_amdgcn_rcpf(e + 1.0f);
    return x * s;
}

// async global->LDS, 16B per lane (LDS dest = wave-uniform base + lane*16)
__device__ __forceinline__ void gload_lds16(const _Float16* g, _Float16* l) {
    __builtin_amdgcn_global_load_lds(
        (const __attribute__((address_space(1))) void*)g,
        (__attribute__((address_space(3))) void*)l, 16, 0, 0);
}

__device__ __forceinline__ void raw_barrier() {
    asm volatile("s_barrier" ::: "memory");
}
__device__ __forceinline__ void lgkm0_barrier() {
    asm volatile("s_waitcnt lgkmcnt(0)" ::: "memory");
    asm volatile("s_barrier" ::: "memory");
}

// ======================= merged prep (round 15) ==============================
// One dispatch replaces 4x transpose_split_fm + prep_emb + e2_kernel (removes
// 5 launch gaps). Block ranges; every segment is an exact multiple of 256.
__device__ __forceinline__ void tsplit_elem(const float* __restrict__ W,
                                            _Float16* __restrict__ Bh,
                                            _Float16* __restrict__ Bl,
                                            int e, int N)
{
    int k = e / N, n = e % N;
    float v = W[e];
    _Float16 h = (_Float16)v;
    _Float16 l = (_Float16)(v - (float)h);
    size_t o = ((size_t)(k >> 3) * N + n) * 8 + (k & 7);
    Bh[o] = h; Bl[o] = l;
}

__global__ __launch_bounds__(256)
void prep_all(const float* __restrict__ w_se, const float* __restrict__ w0,
              const float* __restrict__ w1, const float* __restrict__ w2,
              _Float16* __restrict__ wseh, _Float16* __restrict__ wsel,
              _Float16* __restrict__ w0h, _Float16* __restrict__ w0l,
              _Float16* __restrict__ w1h, _Float16* __restrict__ w1l,
              _Float16* __restrict__ w2h, _Float16* __restrict__ w2l,
              const float* __restrict__ emb, _Float16* __restrict__ ebh,
              _Float16* __restrict__ ebl, float* __restrict__ embT,
              float* __restrict__ e2)
{
    const int b = blockIdx.x, tid = threadIdx.x;
    if (b < 512) {                                   // w_se 256x512
        tsplit_elem(w_se, wseh, wsel, b * 256 + tid, DE);
    } else if (b < 1536) {                           // w0 512x512
        tsplit_elem(w0, w0h, w0l, (b - 512) * 256 + tid, DH);
    } else if (b < 2560) {                           // w1 512x512
        tsplit_elem(w1, w1h, w1l, (b - 1536) * 256 + tid, DH);
    } else if (b < 2688) {                           // w2 512x64
        tsplit_elem(w2, w2h, w2l, (b - 2560) * 256 + tid, DC);
    } else if (b < 2944) {                           // emb -> ebh/ebl/embT
        int e = (b - 2688) * 256 + tid;              // 65536
        int c = e >> 10, n = e & 1023;
        float v = emb[e];
        _Float16 h = (_Float16)v;
        _Float16 l = (_Float16)(v - (float)h);
        ebh[(size_t)n * DC + c] = h;
        ebl[(size_t)n * DC + c] = l;
        embT[(size_t)n * DC + c] = v;
    } else {                                         // e2 (4 blocks)
        int n = (b - 2944) * 256 + tid;              // 1024
        float s = 0.f;
#pragma unroll
        for (int c = 0; c < DC; ++c) { float e = emb[(size_t)c * NCODE + n]; s = fmaf(e, e, s); }
        e2[n] = s;
    }
}

// ======================= MLP GEMM (fp16x3 MFMA, global_load_lds staging) =====
// Round-12 proven configuration (BN=128/BK=32, 32KB LDS, 2 syncthreads/K-step,
// XCD swizzle). 883 TF == 97% of this structure's documented ceiling; round-13
// BK/BN probe confirmed tile aspect (reuse) dominates barrier count here.
template<int BN, bool A_FM, bool EMIT_FM>
__global__ __launch_bounds__(256, 2)
void gemm_fm(const void* __restrict__ A0, const void* __restrict__ A1,
             const _Float16* __restrict__ Bhp, const _Float16* __restrict__ Blp,
             const float* __restrict__ bias,
             void* __restrict__ C0, void* __restrict__ C1,
             int M, int N, int K)
{
    constexpr int BM = 128;
    constexpr int WGM = (BN == 128) ? 2 : 4;
    constexpr int WAVE_M = BM / WGM;
    constexpr int MT = WAVE_M / 16;
    constexpr int NT = 4;
    constexpr int NSHIFT = (BN == 128) ? 7 : 6;
    constexpr int BCALLS = (BN * 4) / 256;     // 16B-chunks per plane / 256 thr

    __shared__ __align__(16) _Float16 As[2][4][BM][8];   // 16 KB
    __shared__ __align__(16) _Float16 Bs[2][4][BN][8];   // 16 or 8 KB

    const int tid  = threadIdx.x;
    const int lane = tid & 63, wid = tid >> 6;
    const int lm   = lane & 15, quad = lane >> 4;
    const int wave_m = (BN == 128) ? (wid & 1) * 64 : wid * 32;
    const int wave_n = (BN == 128) ? (wid >> 1) * 64 : 0;

    // ---- XCD-aware swizzle (bijective; requires gridDim.y % 8 == 0) ----
    int bx = blockIdx.x, by = blockIdx.y;
    if (gridDim.x == 4 && (gridDim.y & 7) == 0) {
        int L = by * 4 + bx;          // linear dispatch id (x-fastest)
        int c = L & 7, w = L >> 3;
        bx = w & 3;                   // member (N-block) 0..3
        by = (w >> 2) * 8 + c;        // A-panel
    }
    const int m0 = by * BM, n0 = bx * BN;

    f32x4 acc[MT][NT];
#pragma unroll
    for (int mi = 0; mi < MT; ++mi)
#pragma unroll
        for (int ni = 0; ni < NT; ++ni) acc[mi][ni] = (f32x4)(0.f);

    for (int k0 = 0; k0 < K; k0 += 32) {
        const int kb0 = k0 >> 3;

        // ---- stage A ----
        if (A_FM) {
            const _Float16* ap[2] = {(const _Float16*)A0, (const _Float16*)A1};
#pragma unroll
            for (int p = 0; p < 2; ++p)
#pragma unroll
                for (int j = 0; j < 2; ++j) {
                    int e  = j * 256 + tid;
                    int kb = e >> 7, tk = e & 127;
                    const _Float16* src = ap[p] + ((size_t)(kb0 + kb) * M + m0 + tk) * 8;
                    int eb = j * 256 + (tid & ~63);
                    gload_lds16(src, &As[p][eb >> 7][eb & 127][0]);
                }
        } else {
            // fp32 A (states): reg-stage + hi/lo split
            const float* A = (const float*)A0;
#pragma unroll
            for (int i = 0; i < 4; ++i) {
                int s = tid + i * 256;
                int row = s >> 3, kc = (s & 7) * 4;
                int kb = kc >> 3, off = kc & 7;
                float4 v = *(const float4*)(A + (size_t)(m0 + row) * K + k0 + kc);
                float vv[4] = {v.x, v.y, v.z, v.w};
                unsigned short h[4], l[4];
#pragma unroll
                for (int j = 0; j < 4; ++j) {
                    _Float16 hh = (_Float16)vv[j];
                    _Float16 ll = (_Float16)(vv[j] - (float)hh);
                    h[j] = __builtin_bit_cast(unsigned short, hh);
                    l[j] = __builtin_bit_cast(unsigned short, ll);
                }
                uint2 ph, pl;
                ph.x = (unsigned int)h[0] | ((unsigned int)h[1] << 16);
                ph.y = (unsigned int)h[2] | ((unsigned int)h[3] << 16);
                pl.x = (unsigned int)l[0] | ((unsigned int)l[1] << 16);
                pl.y = (unsigned int)l[2] | ((unsigned int)l[3] << 16);
                *(uint2*)&As[0][kb][row][off] = ph;
                *(uint2*)&As[1][kb][row][off] = pl;
            }
        }

        // ---- stage B (always fragment-major planes) ----
        {
            const _Float16* bp[2] = {Bhp, Blp};
#pragma unroll
            for (int p = 0; p < 2; ++p)
#pragma unroll
                for (int j = 0; j < BCALLS; ++j) {
                    int e  = j * 256 + tid;
                    int kb = e >> NSHIFT, n = e & (BN - 1);
                    const _Float16* src = bp[p] + ((size_t)(kb0 + kb) * N + n0 + n) * 8;
                    int eb = j * 256 + (tid & ~63);
                    gload_lds16(src, &Bs[p][eb >> NSHIFT][eb & (BN - 1)][0]);
                }
        }
        __syncthreads();

        half8 ahf[MT], alf[MT], bhf[NT], blf[NT];
#pragma unroll
        for (int mi = 0; mi < MT; ++mi) {
            int r = wave_m + mi * 16 + lm;
            ahf[mi] = *(const half8*)&As[0][quad][r][0];
            alf[mi] = *(const half8*)&As[1][quad][r][0];
        }
#pragma unroll
        for (int ni = 0; ni < NT; ++ni) {
            int c = wave_n + ni * 16 + lm;
            bhf[ni] = *(const half8*)&Bs[0][quad][c][0];
            blf[ni] = *(const half8*)&Bs[1][quad][c][0];
        }
#pragma unroll
        for (int mi = 0; mi < MT; ++mi)
#pragma unroll
            for (int ni = 0; ni < NT; ++ni) {
                acc[mi][ni] = __builtin_amdgcn_mfma_f32_16x16x32_f16(ahf[mi], bhf[ni], acc[mi][ni], 0, 0, 0);
                acc[mi][ni] = __builtin_amdgcn_mfma_f32_16x16x32_f16(ahf[mi], blf[ni], acc[mi][ni], 0, 0, 0);
                acc[mi][ni] = __builtin_amdgcn_mfma_f32_16x16x32_f16(alf[mi], bhf[ni], acc[mi][ni], 0, 0, 0);
            }
        __syncthreads();
    }

#pragma unroll
    for (int ni = 0; ni < NT; ++ni) {
        int col = n0 + wave_n + ni * 16 + lm;
        float bv = bias[col];
        size_t slab = EMIT_FM ? ((size_t)(col >> 3) * M * 8 + (col & 7)) : 0;
#pragma unroll
        for (int mi = 0; mi < MT; ++mi) {
            int rowbase = m0 + wave_m + mi * 16 + quad * 4;
#pragma unroll
            for (int r = 0; r < 4; ++r) {
                float g = gelu_f(acc[mi][ni][r] + bv);
                if (EMIT_FM) {
                    _Float16 hh = (_Float16)g;
                    _Float16 ll = (_Float16)(g - (float)hh);
                    size_t oo = slab + (size_t)(rowbase + r) * 8;
                    ((_Float16*)C0)[oo] = hh;
                    ((_Float16*)C1)[oo] = ll;
                } else {
                    ((float*)C0)[(size_t)(rowbase + r) * N + col] = g;
                }
            }
        }
    }
}

// ======================= VQ distance+argmin+quantize (fused, NO count atomics)
__global__ __launch_bounds__(256, 2)
void vq_dist_kernel(const float* __restrict__ lat,
                    const _Float16* __restrict__ ebh, const _Float16* __restrict__ ebl,
                    const float* __restrict__ e2, const float* __restrict__ embT,
                    float* __restrict__ encidx_out, int* __restrict__ codes_out,
                    float* __restrict__ quant_out, float* __restrict__ sum_sq)
{
    __shared__ __align__(16) char Bt[16384];   // staged tile: hi 8KB + lo 8KB (swizzled)
    __shared__ float e2s[NCODE];               // 4096 B
    __shared__ int sidx[128];
    __shared__ float wred[4];

    const int tid = threadIdx.x, lane = tid & 63, wave = tid >> 6;
    const int lm = lane & 15, quad = lane >> 4;
    const int tok0 = blockIdx.x * 128;

    // ---- A fragments: load directly from lat (fp32), split to hi/lo fp16 ----
    half8 ah[2][2], al[2][2];   // [mt][ks]
#pragma unroll
    for (int mt = 0; mt < 2; ++mt)
#pragma unroll
        for (int ks = 0; ks < 2; ++ks) {
            const float* ap = lat + (size_t)(tok0 + wave * 32 + mt * 16 + lm) * DC + ks * 32 + quad * 8;
            float4 v0 = *(const float4*)ap;
            float4 v1 = *(const float4*)(ap + 4);
            float vv[8] = {v0.x, v0.y, v0.z, v0.w, v1.x, v1.y, v1.z, v1.w};
            half8 hh, ll;
#pragma unroll
            for (int j = 0; j < 8; ++j) {
                _Float16 h = (_Float16)vv[j];
                hh[j] = h;
                ll[j] = (_Float16)(vv[j] - (float)h);
            }
            ah[mt][ks] = hh;
            al[mt][ks] = ll;
        }

    // e2 table -> LDS
#pragma unroll
    for (int i = 0; i < 4; ++i) { int k = tid + i * 256; e2s[k] = e2[k]; }

    const _Float16* srcbase[4];
    int ldsoff[4];
#pragma unroll
    for (int k = 0; k < 4; ++k) {
        int S = tid + (k << 8);
        int r = (S & 511) >> 3, c16 = S & 7;
        srcbase[k] = ((S < 512) ? ebh : ebl) + (r << 6) + (c16 << 3);
        ldsoff[k] = ((S >> 9) << 13) + (r << 7) + ((c16 ^ (r & 7)) << 4);
    }

    uint4 stg[4];
#pragma unroll
    for (int k = 0; k < 4; ++k) stg[k] = *(const uint4*)(srcbase[k]);           // tile 0
#pragma unroll
    for (int k = 0; k < 4; ++k) *(uint4*)(Bt + ldsoff[k]) = stg[k];
#pragma unroll
    for (int k = 0; k < 4; ++k) stg[k] = *(const uint4*)(srcbase[k] + 4096);    // tile 1
    lgkm0_barrier();

    const char* Bhi = (const char*)Bt;
    const char* Blo = (const char*)Bt + 8192;

    f32x4 acc[2][4];
    float bd[2][4]; int bi[2][4];
#pragma unroll
    for (int mt = 0; mt < 2; ++mt)
#pragma unroll
        for (int r = 0; r < 4; ++r) { bd[mt][r] = INFINITY; bi[mt][r] = 0; }

    for (int t = 0; t < 16; ++t) {
        const int k0 = t * 64;
#pragma unroll
        for (int mt = 0; mt < 2; ++mt)
#pragma unroll
            for (int ni = 0; ni < 4; ++ni) acc[mt][ni] = (f32x4)(0.f);

#pragma unroll
        for (int ks = 0; ks < 2; ++ks) {
            half8 bh[4], bl[4];
#pragma unroll
            for (int ni = 0; ni < 4; ++ni) {
                int cl = ni * 16 + lm;
                int sw = ((ks * 4 + quad) ^ (cl & 7)) << 4;
                bh[ni] = *(const half8*)(Bhi + (cl << 7) + sw);
                bl[ni] = *(const half8*)(Blo + (cl << 7) + sw);
            }
#pragma unroll
            for (int ni = 0; ni < 4; ++ni)
#pragma unroll
                for (int mt = 0; mt < 2; ++mt) {
                    acc[mt][ni] = __builtin_amdgcn_mfma_f32_16x16x32_f16(ah[mt][ks], bh[ni], acc[mt][ni], 0, 0, 0);
                    acc[mt][ni] = __builtin_amdgcn_mfma_f32_16x16x32_f16(ah[mt][ks], bl[ni], acc[mt][ni], 0, 0, 0);
                    acc[mt][ni] = __builtin_amdgcn_mfma_f32_16x16x32_f16(al[mt][ks], bh[ni], acc[mt][ni], 0, 0, 0);
                    acc[mt][ni] = __builtin_amdgcn_mfma_f32_16x16x32_f16(al[mt][ks], bl[ni], acc[mt][ni], 0, 0, 0);
                }
        }

#pragma unroll
        for (int ni = 0; ni < 4; ++ni) {
            int code = k0 + ni * 16 + lm;
            float ee = e2s[code];
#pragma unroll
            for (int mt = 0; mt < 2; ++mt)
#pragma unroll
                for (int r = 0; r < 4; ++r) {
                    float d = ee - 2.f * acc[mt][ni][r];
                    if (d < bd[mt][r]) { bd[mt][r] = d; bi[mt][r] = code; }
                }
        }

        raw_barrier();
        if (t < 15) {
#pragma unroll
            for (int k = 0; k < 4; ++k) *(uint4*)(Bt + ldsoff[k]) = stg[k];    // tile t+1
            if (t < 14) {
#pragma unroll
                for (int k = 0; k < 4; ++k)
                    stg[k] = *(const uint4*)(srcbase[k] + (size_t)(t + 2) * 4096);
            }
            lgkm0_barrier();
        }
    }

    // argmin across the 16 lanes of each quad-group via shfl_xor
#pragma unroll
    for (int mt = 0; mt < 2; ++mt)
#pragma unroll
        for (int r = 0; r < 4; ++r) {
            float d = bd[mt][r]; int i0 = bi[mt][r];
#pragma unroll
            for (int off = 1; off < 16; off <<= 1) {
                float od = __shfl_xor(d, off, 64);
                int   oi = __shfl_xor(i0, off, 64);
                if (od < d || (od == d && oi < i0)) { d = od; i0 = oi; }
            }
            if (lm == 0) {
                int tok = wave * 32 + mt * 16 + quad * 4 + r;
                sidx[tok] = i0;
                encidx_out[tok0 + tok] = (float)i0;
                codes_out[tok0 + tok] = i0;
            }
        }
    __syncthreads();

    // ---- quantize + e_latent_loss (exact fp32 embT gather) ----
    const int t2 = tid >> 1;        // token 0..127
    const int g  = tid & 1;         // half of the 64 dims
    const int code = sidx[t2];
    float lsum = 0.f;
#pragma unroll
    for (int q = 0; q < 4; ++q) {
        int c0 = g * 32 + q * 8;
        const size_t tb = (size_t)(tok0 + t2) * DC + c0;
        float4 x0 = *(const float4*)(lat + tb);
        float4 x1 = *(const float4*)(lat + tb + 4);
        float4 e0 = *(const float4*)(embT + (size_t)code * DC + c0);
        float4 e1 = *(const float4*)(embT + (size_t)code * DC + c0 + 4);
        float xx[8] = {x0.x, x0.y, x0.z, x0.w, x1.x, x1.y, x1.z, x1.w};
        float qq[8] = {e0.x, e0.y, e0.z, e0.w, e1.x, e1.y, e1.z, e1.w};
#pragma unroll
        for (int j = 0; j < 8; ++j) {
            float d = qq[j] - xx[j];
            lsum = fmaf(d, d, lsum);
        }
        *(float4*)(quant_out + tb) = e0;
        *(float4*)(quant_out + tb + 4) = e1;
    }
#pragma unroll
    for (int o = 32; o > 0; o >>= 1) lsum += __shfl_down(lsum, o);
    if (lane == 0) wred[wave] = lsum;
    __syncthreads();
    if (tid == 0) atomicAdd(sum_sq, wred[0] + wred[1] + wred[2] + wred[3]);
}

// ======================= histogram + rank (non-atomic counts) ================
__global__ __launch_bounds__(256)
void hist_rank_kernel(const int* __restrict__ codes, int* __restrict__ crank,
                      unsigned int* __restrict__ hist2d)
{
    __shared__ unsigned int hist[NCODE];
    const int tid = threadIdx.x, b = blockIdx.x;
#pragma unroll
    for (int j = 0; j < 4; ++j) hist[tid + j * 256] = 0;
    __syncthreads();
#pragma unroll
    for (int j = 0; j < 4; ++j) {
        int t = b * 1024 + j * 256 + tid;
        int c = codes[t];
        crank[t] = (int)atomicAdd(&hist[c], 1u);   // LDS atomic
    }
    __syncthreads();
#pragma unroll
    for (int j = 0; j < 4; ++j) {
        int k = tid + j * 256;
        hist2d[(size_t)b * NCODE + k] = hist[k];
    }
}

// ======================= scan: counts, offs, per-block bases =================
__global__ __launch_bounds__(1024)
void scan_kernel(const unsigned int* __restrict__ hist2d,
                 unsigned int* __restrict__ counts, int* __restrict__ offs,
                 int* __restrict__ base2d)
{
    __shared__ int s[1024];
    const int t = threadIdx.x;
    int v = 0;
    for (int b = 0; b < HBLK; ++b) v += (int)hist2d[(size_t)b * NCODE + t];
    counts[t] = (unsigned int)v;
    s[t] = v; __syncthreads();
    for (int d = 1; d < 1024; d <<= 1) {
        int x = (t >= d) ? s[t - d] : 0;
        __syncthreads();
        s[t] += x;
        __syncthreads();
    }
    int run = s[t] - v;          // exclusive prefix
    offs[t] = run;
    for (int b = 0; b < HBLK; ++b) {
        base2d[(size_t)b * NCODE + t] = run;
        run += (int)hist2d[(size_t)b * NCODE + t];
    }
}

// ======================= scatter (atomic-free) ===============================
__global__ __launch_bounds__(256)
void scatter_kernel(const int* __restrict__ codes, const int* __restrict__ crank,
                    const int* __restrict__ base2d, int* __restrict__ bucket)
{
    const int tid = threadIdx.x, b = blockIdx.x;
#pragma unroll
    for (int j = 0; j < 4; ++j) {
        int t = b * 1024 + j * 256 + tid;
        int c = codes[t];
        bucket[base2d[(size_t)b * NCODE + c] + crank[t]] = t;
    }
}

// grid (NCODE, NTOK/DWCHUNK); skew-proof (round-5 lesson: do not regrid).
__global__ __launch_bounds__(256)
void dw_kernel(const float* __restrict__ lat, const int* __restrict__ bucket,
               const int* __restrict__ offs, const unsigned int* __restrict__ counts,
               float* __restrict__ dw)
{
    __shared__ float sred[4][64];
    const int code = blockIdx.x;
    const int n = (int)counts[code];
    const int start = blockIdx.y * DWCHUNK;
    if (start >= n) return;
    const int cnt = min(n - start, DWCHUNK);
    const int base = offs[code] + start;
    const int lane = threadIdx.x & 63, wave = threadIdx.x >> 6;

    float s0 = 0.f, s1 = 0.f, s2 = 0.f, s3 = 0.f;
    int i = wave;
    for (; i + 12 < cnt; i += 16) {
        int t0 = bucket[base + i];
        int t1 = bucket[base + i + 4];
        int t2 = bucket[base + i + 8];
        int t3 = bucket[base + i + 12];
        s0 += lat[(size_t)t0 * DC + lane];
        s1 += lat[(size_t)t1 * DC + lane];
        s2 += lat[(size_t)t2 * DC + lane];
        s3 += lat[(size_t)t3 * DC + lane];
    }
    for (; i < cnt; i += 4)
        s0 += lat[(size_t)bucket[base + i] * DC + lane];

    sred[wave][lane] = (s0 + s1) + (s2 + s3);
    __syncthreads();
    if (threadIdx.x < 64) {
        float tot = sred[0][lane] + sred[1][lane] + sred[2][lane] + sred[3][lane];
        atomicAdd(&dw[(size_t)lane * NCODE + code], tot);
    }
}

// ======================= finalize (round 15: split) ==========================
// 1-block scalar pass: n (written to scalars), loss, perplexity. Reductions
// identical to the old fused finalize -> bit-identical outputs.
__global__ __launch_bounds__(1024)
void finalize_scalars(const unsigned int* __restrict__ counts,
                      const float* __restrict__ ema_ch,
                      const float* __restrict__ sum_sq,
                      float* __restrict__ nbuf,
                      float* __restrict__ out_loss, float* __restrict__ out_perp)
{
    __shared__ float sred[1024];
    const int k = threadIdx.x;
    const float debias = (float)(1.0 - pow(0.99, 1001.0));
    float cnt = (float)counts[k];
    float cs  = (ema_ch[k] * 0.99f + cnt * 0.01f) / debias;

    sred[k] = cs; __syncthreads();
    for (int s = 512; s > 0; s >>= 1) { if (k < s) sred[k] += sred[k + s]; __syncthreads(); }
    float n = sred[0];
    __syncthreads();

    float p = cnt / 98304.0f;
    sred[k] = p * logf(p + 1e-10f);
    __syncthreads();
    for (int s = 512; s > 0; s >>= 1) { if (k < s) sred[k] += sred[k + s]; __syncthreads(); }
    if (k == 0) {
        nbuf[0] = n;
        out_perp[0] = expf(-sred[0]);
        out_loss[0] = 0.25f * sum_sq[0] / 6291456.0f;
    }
}

// Parallel newemb: 256 blocks x 256 threads, one element each (coalesced).
// Per-element float ops identical to the old serial loop -> bit-identical.
__global__ __launch_bounds__(256)
void newemb_kernel(const unsigned int* __restrict__ counts,
                   const float* __restrict__ dw,
                   const float* __restrict__ ema_ch,
                   const float* __restrict__ ema_dw,
                   const float* __restrict__ nbuf,
                   float* __restrict__ out_newemb)
{
    const int e = blockIdx.x * 256 + threadIdx.x;   // 65536
    const int k = e & 1023;
    const float debias = (float)(1.0 - pow(0.99, 1001.0));
    float cs = (ema_ch[k] * 0.99f + (float)counts[k] * 0.01f) / debias;
    float n = nbuf[0];
    float stable = (cs + 1e-5f) / (n + 1024.0f * 1e-5f) * n;
    out_newemb[e] = ((ema_dw[e] * 0.99f + dw[e] * 0.01f) / debias) / stable;
}

extern "C" void kernel_launch(void* const* d_in, const int* in_sizes, int n_in,
                              void* d_out, int out_size, void* d_ws, size_t ws_size,
                              hipStream_t stream)
{
    (void)in_sizes; (void)n_in; (void)out_size; (void)ws_size;
    const float* states = (const float*)d_in[0];
    const float* w_se   = (const float*)d_in[1];
    const float* b_se   = (const float*)d_in[2];
    const float* w0     = (const float*)d_in[3];
    const float* b0     = (const float*)d_in[4];
    const float* w1     = (const float*)d_in[5];
    const float* b1     = (const float*)d_in[6];
    const float* w2     = (const float*)d_in[7];
    const float* b2     = (const float*)d_in[8];
    const float* emb    = (const float*)d_in[9];
    const float* ema_ch = (const float*)d_in[10];
    const float* ema_dw = (const float*)d_in[11];

    float* out        = (float*)d_out;
    float* q_out      = out;                    // 6291456
    float* loss_out   = out + 6291456;          // 1
    float* perp_out   = out + 6291457;          // 1
    float* idx_out    = out + 6291458;          // 98304
    float* newemb_out = out + 6389762;          // 65536

    // ---- workspace layout (zeroed prefix first) ----
    char* ws = (char*)d_ws;
    size_t o = 0;
    unsigned int* counts  = (unsigned int*)(ws + o); o += 4096;
    float*        sumsq   = (float*)(ws + o);        o += 256;   // [0]=sumsq, [1]=n
    float*        dwb     = (float*)(ws + o);        o += (size_t)DC * NCODE * 4;  // zeroed
    const size_t ZERO_BYTES = o;
    int*          offs    = (int*)(ws + o);          o += 4096;
    int*          codes   = (int*)(ws + o);          o += (size_t)NTOK * 4;
    int*          crank   = (int*)(ws + o);          o += (size_t)NTOK * 4;
    int*          bucket  = (int*)(ws + o);          o += (size_t)NTOK * 4;
    float*        e2b     = (float*)(ws + o);        o += 4096;
    unsigned int* hist2d  = (unsigned int*)(ws + o); o += (size_t)HBLK * NCODE * 4;
    int*          base2d  = (int*)(ws + o);          o += (size_t)HBLK * NCODE * 4;
    _Float16*     ebh     = (_Float16*)(ws + o);     o += (size_t)NCODE * DC * 2;
    _Float16*     ebl     = (_Float16*)(ws + o);     o += (size_t)NCODE * DC * 2;
    float*        embT    = (float*)(ws + o);        o += (size_t)NCODE * DC * 4;
    _Float16*     wseh    = (_Float16*)(ws + o);     o += (size_t)DIN * DE * 2;
    _Float16*     wsel    = (_Float16*)(ws + o);     o += (size_t)DIN * DE * 2;
    _Float16*     w0h     = (_Float16*)(ws + o);     o += (size_t)DE * DH * 2;
    _Float16*     w0l     = (_Float16*)(ws + o);     o += (size_t)DE * DH * 2;
    _Float16*     w1h     = (_Float16*)(ws + o);     o += (size_t)DH * DH * 2;
    _Float16*     w1l     = (_Float16*)(ws + o);     o += (size_t)DH * DH * 2;
    _Float16*     w2h     = (_Float16*)(ws + o);     o += (size_t)DH * DC * 2;
    _Float16*     w2l     = (_Float16*)(ws + o);     o += (size_t)DH * DC * 2;
    _Float16*     bufAh   = (_Float16*)(ws + o);     o += (size_t)CHUNK * DE * 2;
    _Float16*     bufAl   = (_Float16*)(ws + o);     o += (size_t)CHUNK * DE * 2;
    _Float16*     bufBh   = (_Float16*)(ws + o);     o += (size_t)CHUNK * DH * 2;
    _Float16*     bufBl   = (_Float16*)(ws + o);     o += (size_t)CHUNK * DH * 2;
    float*        lat     = (float*)(ws + o);        o += (size_t)NTOK * DC * 4;

    hipMemsetAsync(d_ws, 0, ZERO_BYTES, stream);

    // merged prep (replaces 6 tiny dispatches)
    prep_all<<<dim3(2948), dim3(256), 0, stream>>>(
        w_se, w0, w1, w2, wseh, wsel, w0h, w0l, w1h, w1l, w2h, w2l,
        emb, ebh, ebl, embT, e2b);

    dim3 blk(256);
    const int MBLK = CHUNK / 128;
    for (int c = 0; c < NTOK / CHUNK; ++c) {
        size_t off = (size_t)c * CHUNK;
        gemm_fm<128, false, true><<<dim3(DE / 128, MBLK), blk, 0, stream>>>(
            states + off * DIN, nullptr, wseh, wsel, b_se, bufAh, bufAl, CHUNK, DE, DIN);
        gemm_fm<128, true, true><<<dim3(DH / 128, MBLK), blk, 0, stream>>>(
            bufAh, bufAl, w0h, w0l, b0, bufBh, bufBl, CHUNK, DH, DE);
        gemm_fm<128, true, true><<<dim3(DH / 128, MBLK), blk, 0, stream>>>(
            bufBh, bufBl, w1h, w1l, b1, bufAh, bufAl, CHUNK, DH, DH);
        gemm_fm<64, true, false><<<dim3(1, MBLK), blk, 0, stream>>>(
            bufAh, bufAl, w2h, w2l, b2, lat + off * DC, nullptr, CHUNK, DC, DH);
    }

    vq_dist_kernel<<<dim3(NTOK / 128), blk, 0, stream>>>(
        lat, ebh, ebl, e2b, embT, idx_out, codes, q_out, sumsq);

    hist_rank_kernel<<<dim3(HBLK), blk, 0, stream>>>(codes, crank, hist2d);
    scan_kernel<<<dim3(1), dim3(1024), 0, stream>>>(hist2d, counts, offs, base2d);
    scatter_kernel<<<dim3(HBLK), blk, 0, stream>>>(codes, crank, base2d, bucket);
    dw_kernel<<<dim3(NCODE, NTOK / DWCHUNK), blk, 0, stream>>>(lat, bucket, offs, counts, dwb);

    finalize_scalars<<<dim3(1), dim3(1024), 0, stream>>>(counts, ema_ch, sumsq,
                                                         sumsq + 1, loss_out, perp_out);
    newemb_kernel<<<dim3(256), blk, 0, stream>>>(counts, dwb, ema_ch, ema_dw,
                                                 sumsq + 1, newemb_out);
}